// Round 1
// baseline (736.424 us; speedup 1.0000x reference)
//
#include <hip/hip_runtime.h>
#include <cstdint>

// ---------------------------------------------------------------------------
// GCNRecommender: 3x GCNConv(+LN+ELU) -> Linear(+LN+ELU) -> Linear
// Strategy round 1 (fp32 correctness-first):
//  - CSR build per launch (deg count -> scan -> fill), gather-based aggregation
//  - All aggregations at F=128 (aggregate before GEMM when out>in, after when in>out)
//  - Generic tiled fp32 GEMM (BM=64,BN=64,BK=16, 4x4/thread)
//  - Fused-free LN+ELU rowwise kernel
// ---------------------------------------------------------------------------

#define LN_EPS 1e-5f

__global__ void zero2_kernel(int* __restrict__ a, int* __restrict__ b, int n) {
  int i = blockIdx.x * blockDim.x + threadIdx.x;
  if (i < n) { a[i] = 0; b[i] = 0; }
}

__global__ void deg_kernel(const int* __restrict__ dst, int* __restrict__ deg, int E) {
  int e = blockIdx.x * blockDim.x + threadIdx.x;
  if (e < E) atomicAdd(&deg[dst[e]], 1);
}

__global__ void dinv_kernel(const int* __restrict__ deg, float* __restrict__ dinv, int N) {
  int n = blockIdx.x * blockDim.x + threadIdx.x;
  if (n < N) dinv[n] = rsqrtf((float)deg[n] + 1.0f);  // +1 self-loop; deg+1 > 0 always
}

// exclusive scan, 3-kernel hierarchy (N=50000 -> 196 blocks of 256)
__global__ void scan1_kernel(const int* __restrict__ deg, int* __restrict__ excl,
                             int* __restrict__ bsums, int N) {
  __shared__ int s[256];
  int tid = threadIdx.x;
  int i = blockIdx.x * 256 + tid;
  int v = (i < N) ? deg[i] : 0;
  s[tid] = v;
  __syncthreads();
  for (int o = 1; o < 256; o <<= 1) {
    int t = (tid >= o) ? s[tid - o] : 0;
    __syncthreads();
    if (tid >= o) s[tid] += t;
    __syncthreads();
  }
  if (i < N) excl[i] = s[tid] - v;
  if (tid == 255) bsums[blockIdx.x] = s[tid];
}

__global__ void scan2_kernel(int* __restrict__ bsums, int nb) {
  __shared__ int s[256];
  int tid = threadIdx.x;
  int v = (tid < nb) ? bsums[tid] : 0;
  s[tid] = v;
  __syncthreads();
  for (int o = 1; o < 256; o <<= 1) {
    int t = (tid >= o) ? s[tid - o] : 0;
    __syncthreads();
    if (tid >= o) s[tid] += t;
    __syncthreads();
  }
  if (tid < nb) bsums[tid] = s[tid] - v;
}

__global__ void scan3_kernel(int* __restrict__ rowptr, const int* __restrict__ bsums,
                             int N, int Etotal) {
  int i = blockIdx.x * blockDim.x + threadIdx.x;
  if (i < N) rowptr[i] += bsums[i >> 8];
  else if (i == N) rowptr[N] = Etotal;
}

__global__ void fill_kernel(const int* __restrict__ src, const int* __restrict__ dst,
                            const int* __restrict__ rowptr, int* __restrict__ fill,
                            const float* __restrict__ dinv, int* __restrict__ srcs,
                            float* __restrict__ coefs, int E) {
  int e = blockIdx.x * blockDim.x + threadIdx.x;
  if (e >= E) return;
  int d = dst[e];
  int s = src[e];
  int pos = atomicAdd(&fill[d], 1);
  int idx = rowptr[d] + pos;
  srcs[idx] = s;
  coefs[idx] = dinv[s] * dinv[d];
}

// Aggregation at F=128: out[n,:] = sum_{e in N(n)} coef_e * h[src_e,:] + dinv[n]^2 * h[n,:] (+ bias)
__global__ __launch_bounds__(128) void agg_kernel(
    const float* __restrict__ h, const int* __restrict__ rowptr,
    const int* __restrict__ srcs, const float* __restrict__ coefs,
    const float* __restrict__ dinv, const float* __restrict__ bias,
    float* __restrict__ out) {
  const int n = blockIdx.x;
  const int f = threadIdx.x;
  const float di = dinv[n];
  float acc = h[(size_t)n * 128 + f] * di * di;
  if (bias) acc += bias[f];
  const int s0 = rowptr[n], s1 = rowptr[n + 1];
  int i = s0;
  for (; i + 3 < s1; i += 4) {
    int a0 = srcs[i], a1 = srcs[i + 1], a2 = srcs[i + 2], a3 = srcs[i + 3];
    float c0 = coefs[i], c1 = coefs[i + 1], c2 = coefs[i + 2], c3 = coefs[i + 3];
    float v0 = h[(size_t)a0 * 128 + f];
    float v1 = h[(size_t)a1 * 128 + f];
    float v2 = h[(size_t)a2 * 128 + f];
    float v3 = h[(size_t)a3 * 128 + f];
    acc += c0 * v0 + c1 * v1 + c2 * v2 + c3 * v3;
  }
  for (; i < s1; i++) acc += coefs[i] * h[(size_t)srcs[i] * 128 + f];
  out[(size_t)n * 128 + f] = acc;
}

// Generic fp32 GEMM: C[M,N] = A[M,K] @ B[K,N] (+ bias). K % 16 == 0, N % 4 == 0.
#define BM 64
#define BN 64
#define BK 16
__global__ __launch_bounds__(256) void gemm_kernel(
    const float* __restrict__ A, const float* __restrict__ B,
    const float* __restrict__ bias, float* __restrict__ C,
    int M, int N, int K) {
  __shared__ float As[BK][BM + 4];  // +4 keeps float4 alignment (stride 68*4 bytes)
  __shared__ float Bs[BK][BN + 4];
  const int tid = threadIdx.x;
  const int rowBase = blockIdx.y * BM;
  const int colBase = blockIdx.x * BN;
  const int tx = tid & 15;      // 0..15 -> 4 cols each
  const int ty = tid >> 4;      // 0..15 -> 4 rows each
  // A tile load mapping: 64x16 = 256 float4
  const int ar = tid >> 2;            // 0..63 row in tile
  const int ac4 = (tid & 3) * 4;      // 0,4,8,12 k offset
  // B tile load mapping: 16x64 = 256 float4
  const int br = tid >> 4;            // 0..15 k row
  const int bc4 = (tid & 15) * 4;     // 0..60 col offset
  float acc[4][4] = {};
  for (int k0 = 0; k0 < K; k0 += BK) {
    {
      int row = rowBase + ar;
      float4 v = make_float4(0.f, 0.f, 0.f, 0.f);
      if (row < M) v = *(const float4*)(A + (size_t)row * K + k0 + ac4);
      As[ac4 + 0][ar] = v.x;
      As[ac4 + 1][ar] = v.y;
      As[ac4 + 2][ar] = v.z;
      As[ac4 + 3][ar] = v.w;
    }
    {
      int col = colBase + bc4;
      int krow = k0 + br;
      float4 v = make_float4(0.f, 0.f, 0.f, 0.f);
      if (col + 3 < N) {
        v = *(const float4*)(B + (size_t)krow * N + col);
      } else {
        float t0 = (col + 0 < N) ? B[(size_t)krow * N + col + 0] : 0.f;
        float t1 = (col + 1 < N) ? B[(size_t)krow * N + col + 1] : 0.f;
        float t2 = (col + 2 < N) ? B[(size_t)krow * N + col + 2] : 0.f;
        float t3 = (col + 3 < N) ? B[(size_t)krow * N + col + 3] : 0.f;
        v = make_float4(t0, t1, t2, t3);
      }
      Bs[br][bc4 + 0] = v.x;
      Bs[br][bc4 + 1] = v.y;
      Bs[br][bc4 + 2] = v.z;
      Bs[br][bc4 + 3] = v.w;
    }
    __syncthreads();
#pragma unroll
    for (int kk = 0; kk < BK; kk++) {
      float4 a4 = *(const float4*)&As[kk][ty * 4];
      float4 b4 = *(const float4*)&Bs[kk][tx * 4];
      float a[4] = {a4.x, a4.y, a4.z, a4.w};
      float b[4] = {b4.x, b4.y, b4.z, b4.w};
#pragma unroll
      for (int i = 0; i < 4; i++)
#pragma unroll
        for (int j = 0; j < 4; j++) acc[i][j] += a[i] * b[j];
    }
    __syncthreads();
  }
#pragma unroll
  for (int i = 0; i < 4; i++) {
    int row = rowBase + ty * 4 + i;
    if (row >= M) continue;
#pragma unroll
    for (int j = 0; j < 4; j++) {
      int col = colBase + tx * 4 + j;
      if (col >= N) continue;
      float v = acc[i][j];
      if (bias) v += bias[col];
      C[(size_t)row * N + col] = v;
    }
  }
}

// Rowwise LayerNorm + ELU (in-place). Block = F threads.
template <int F>
__global__ __launch_bounds__(F) void ln_elu_kernel(float* __restrict__ x,
                                                   const float* __restrict__ g,
                                                   const float* __restrict__ be) {
  constexpr int NW = F / 64;
  __shared__ float sb[NW > 0 ? NW : 1];
  const int row = blockIdx.x;
  const int f = threadIdx.x;
  float v = x[(size_t)row * F + f];
  float s = v;
#pragma unroll
  for (int o = 32; o >= 1; o >>= 1) s += __shfl_xor(s, o);
  float mean;
  if constexpr (NW == 1) {
    mean = s * (1.0f / F);
  } else {
    if ((f & 63) == 0) sb[f >> 6] = s;
    __syncthreads();
    float t = 0.f;
#pragma unroll
    for (int w = 0; w < NW; w++) t += sb[w];
    mean = t * (1.0f / F);
    __syncthreads();
  }
  float d = v - mean;
  float q = d * d;
#pragma unroll
  for (int o = 32; o >= 1; o >>= 1) q += __shfl_xor(q, o);
  float var;
  if constexpr (NW == 1) {
    var = q * (1.0f / F);
  } else {
    if ((f & 63) == 0) sb[f >> 6] = q;
    __syncthreads();
    float t = 0.f;
#pragma unroll
    for (int w = 0; w < NW; w++) t += sb[w];
    var = t * (1.0f / F);
  }
  float y = d * rsqrtf(var + LN_EPS) * g[f] + be[f];
  x[(size_t)row * F + f] = (y > 0.f) ? y : expm1f(y);
}

extern "C" void kernel_launch(void* const* d_in, const int* in_sizes, int n_in,
                              void* d_out, int out_size, void* d_ws, size_t ws_size,
                              hipStream_t stream) {
  const float* x   = (const float*)d_in[0];
  const int*   ei  = (const int*)d_in[1];
  const float* W1  = (const float*)d_in[2];
  const float* b1  = (const float*)d_in[3];
  const float* g1  = (const float*)d_in[4];
  const float* be1 = (const float*)d_in[5];
  const float* W2  = (const float*)d_in[6];
  const float* b2  = (const float*)d_in[7];
  const float* g2  = (const float*)d_in[8];
  const float* be2 = (const float*)d_in[9];
  const float* W3  = (const float*)d_in[10];
  const float* b3  = (const float*)d_in[11];
  const float* g3  = (const float*)d_in[12];
  const float* be3 = (const float*)d_in[13];
  const float* Wl1 = (const float*)d_in[14];
  const float* bl1 = (const float*)d_in[15];
  const float* g4  = (const float*)d_in[16];
  const float* be4 = (const float*)d_in[17];
  const float* Wl2 = (const float*)d_in[18];
  const float* bl2 = (const float*)d_in[19];

  const int N = in_sizes[0] / 128;  // 50000
  const int E = in_sizes[1] / 2;    // 800000
  const int* esrc = ei;
  const int* edst = ei + E;

  // workspace layout
  float* bufA  = (float*)d_ws;                       // N*256 floats
  float* bufB  = bufA + (size_t)N * 256;             // N*256 floats
  int*   srcs  = (int*)(bufB + (size_t)N * 256);     // E
  float* coefs = (float*)(srcs + E);                 // E
  int*   deg   = (int*)(coefs + E);                  // N
  float* dinv  = (float*)(deg + N);                  // N
  int*   rowptr= (int*)(dinv + N);                   // N+1
  int*   fill  = rowptr + N + 2;                     // N
  int*   bsums = fill + N;                           // <=256

  const int nb = (N + 255) / 256;  // 196
  const int eb = (E + 255) / 256;

  // ---- CSR build (shared by all 3 convs) ----
  zero2_kernel<<<nb, 256, 0, stream>>>(deg, fill, N);
  deg_kernel<<<eb, 256, 0, stream>>>(edst, deg, E);
  dinv_kernel<<<nb, 256, 0, stream>>>(deg, dinv, N);
  scan1_kernel<<<nb, 256, 0, stream>>>(deg, rowptr, bsums, N);
  scan2_kernel<<<1, 256, 0, stream>>>(bsums, nb);
  scan3_kernel<<<(N + 256) / 256, 256, 0, stream>>>(rowptr, bsums, N, E);
  fill_kernel<<<eb, 256, 0, stream>>>(esrc, edst, rowptr, fill, dinv, srcs, coefs, E);

  auto gemm = [&](const float* A, const float* B, const float* bias, float* C,
                  int M, int Nn, int K) {
    dim3 grid((Nn + BN - 1) / BN, (M + BM - 1) / BM);
    gemm_kernel<<<grid, 256, 0, stream>>>(A, B, bias, C, M, Nn, K);
  };

  // ---- Layer 1: h1 = elu(LN(Agg(x@W1) + b1)) ----
  gemm(x, W1, nullptr, bufA, N, 128, 128);
  agg_kernel<<<N, 128, 0, stream>>>(bufA, rowptr, srcs, coefs, dinv, b1, bufB);
  ln_elu_kernel<128><<<N, 128, 0, stream>>>(bufB, g1, be1);

  // ---- Layer 2 (aggregate first, 128 < 256): h2 = elu(LN(Agg(h1)@W2 + b2)) ----
  agg_kernel<<<N, 128, 0, stream>>>(bufB, rowptr, srcs, coefs, dinv, nullptr, bufA);
  gemm(bufA, W2, b2, bufB, N, 256, 128);
  ln_elu_kernel<256><<<N, 256, 0, stream>>>(bufB, g2, be2);

  // ---- Layer 3 (GEMM first, 256 > 128): h3 = elu(LN(Agg(h2@W3) + b3)) ----
  gemm(bufB, W3, nullptr, bufA, N, 128, 256);
  agg_kernel<<<N, 128, 0, stream>>>(bufA, rowptr, srcs, coefs, dinv, b3, bufB);
  ln_elu_kernel<128><<<N, 128, 0, stream>>>(bufB, g3, be3);

  // ---- Layer 4: h4 = elu(LN(h3@Wl1 + bl1)) ----
  gemm(bufB, Wl1, bl1, bufA, N, 64, 128);
  ln_elu_kernel<64><<<N, 64, 0, stream>>>(bufA, g4, be4);

  // ---- Layer 5: out = h4@Wl2 + bl2 ----
  gemm(bufA, Wl2, bl2, (float*)d_out, N, 500, 64);
}

// Round 2
// 575.315 us; speedup vs baseline: 1.2800x; 1.2800x over previous
//
#include <hip/hip_runtime.h>
#include <cstdint>

// ---------------------------------------------------------------------------
// GCNRecommender round 2: bf16 MFMA pipeline.
//  - All GEMMs via v_mfma_f32_16x16x32_bf16, 128x128 block tile, 4 waves.
//  - Weights transposed+converted to bf16 [N][K] once per launch (tiny).
//  - Activations bf16 everywhere; agg accumulates fp32; LN accumulates fp32.
//  - CSR gather aggregation (1 wave per node, 2 features per lane as uint).
// ---------------------------------------------------------------------------

#define LN_EPS 1e-5f

typedef __attribute__((ext_vector_type(8))) short bf16x8;
typedef __attribute__((ext_vector_type(4))) float f32x4;

static __device__ __forceinline__ ushort f2bf(float f) {
  union { float f; uint u; } c; c.f = f;
  uint u = c.u;
  return (ushort)((u + 0x7fffu + ((u >> 16) & 1u)) >> 16);  // RNE
}
static __device__ __forceinline__ float bf2f(ushort h) {
  union { uint u; float f; } c; c.u = (uint)h << 16;
  return c.f;
}

// ---------------- CSR build ----------------

__global__ void zero2_kernel(int* __restrict__ a, int* __restrict__ b, int n) {
  int i = blockIdx.x * blockDim.x + threadIdx.x;
  if (i < n) { a[i] = 0; b[i] = 0; }
}

__global__ void deg_kernel(const int* __restrict__ dst, int* __restrict__ deg, int E) {
  int e = blockIdx.x * blockDim.x + threadIdx.x;
  if (e < E) atomicAdd(&deg[dst[e]], 1);
}

__global__ void scan1_kernel(const int* __restrict__ deg, int* __restrict__ excl,
                             int* __restrict__ bsums, float* __restrict__ dinv, int N) {
  __shared__ int s[256];
  int tid = threadIdx.x;
  int i = blockIdx.x * 256 + tid;
  int v = (i < N) ? deg[i] : 0;
  s[tid] = v;
  __syncthreads();
  for (int o = 1; o < 256; o <<= 1) {
    int t = (tid >= o) ? s[tid - o] : 0;
    __syncthreads();
    if (tid >= o) s[tid] += t;
    __syncthreads();
  }
  if (i < N) {
    excl[i] = s[tid] - v;
    dinv[i] = rsqrtf((float)v + 1.0f);  // +1 self-loop
  }
  if (tid == 255) bsums[blockIdx.x] = s[tid];
}

__global__ void scan2_kernel(int* __restrict__ bsums, int nb) {
  __shared__ int s[256];
  int tid = threadIdx.x;
  int v = (tid < nb) ? bsums[tid] : 0;
  s[tid] = v;
  __syncthreads();
  for (int o = 1; o < 256; o <<= 1) {
    int t = (tid >= o) ? s[tid - o] : 0;
    __syncthreads();
    if (tid >= o) s[tid] += t;
    __syncthreads();
  }
  if (tid < nb) bsums[tid] = s[tid] - v;
}

__global__ void scan3_kernel(int* __restrict__ rowptr, const int* __restrict__ bsums,
                             int N, int Etotal) {
  int i = blockIdx.x * blockDim.x + threadIdx.x;
  if (i < N) rowptr[i] += bsums[i >> 8];
  else if (i == N) rowptr[N] = Etotal;
}

__global__ void fill_kernel(const int* __restrict__ src, const int* __restrict__ dst,
                            const int* __restrict__ rowptr, int* __restrict__ fill,
                            const float* __restrict__ dinv, int* __restrict__ srcs,
                            float* __restrict__ coefs, int E) {
  int e = blockIdx.x * blockDim.x + threadIdx.x;
  if (e >= E) return;
  int d = dst[e];
  int s = src[e];
  int pos = atomicAdd(&fill[d], 1);
  int idx = rowptr[d] + pos;
  srcs[idx] = s;
  coefs[idx] = dinv[s] * dinv[d];
}

// ---------------- conversions ----------------

__global__ void f2bf_vec_kernel(const float* __restrict__ in, ushort* __restrict__ out, int n4) {
  int i = blockIdx.x * blockDim.x + threadIdx.x;
  if (i >= n4) return;
  float4 v = ((const float4*)in)[i];
  ushort4 o;
  o.x = f2bf(v.x); o.y = f2bf(v.y); o.z = f2bf(v.z); o.w = f2bf(v.w);
  ((ushort4*)out)[i] = o;
}

struct WConvArgs {
  const float* w[5];
  ushort* wt[5];
  int K[5], N[5];
  int off[6];  // exclusive prefix of K*N
};

// W[K][N] fp32 -> Wt[N][K] bf16, all 5 weight matrices in one launch
__global__ void wconv_kernel(WConvArgs a, int total) {
  int i = blockIdx.x * blockDim.x + threadIdx.x;
  if (i >= total) return;
  int m = 0;
  while (i >= a.off[m + 1]) m++;
  int j = i - a.off[m];
  int k = j / a.N[m], n = j - k * a.N[m];
  a.wt[m][(size_t)n * a.K[m] + k] = f2bf(a.w[m][j]);
}

// ---------------- bf16 MFMA GEMM ----------------
// C[M][N] = A[M][K] @ Bt[N][K]^T (+ bias). K % 32 == 0.
// Block 128x128, 256 threads = 4 waves in 2x2, each wave 64x64 via 4x4 MFMAs.
#define TBM 128
#define TBN 128
#define TBK 32
#define LDK 40  // pad: stride 80 B breaks 16-row bank alias (20 banks/row)

template <bool OUT_BF16>
__global__ __launch_bounds__(256, 2) void mfma_gemm_kernel(
    const ushort* __restrict__ A, const ushort* __restrict__ Bt,
    const float* __restrict__ bias, void* __restrict__ Cout,
    int M, int N, int K) {
  __shared__ ushort As[TBM][LDK];
  __shared__ ushort Bs[TBN][LDK];
  const int tid = threadIdx.x;
  const int lane = tid & 63;
  const int w = tid >> 6;
  const int wm = w & 1, wn = w >> 1;
  const int quad = lane >> 4, l16 = lane & 15;
  const int rowBase = blockIdx.y * TBM;
  const int colBase = blockIdx.x * TBN;

  f32x4 acc[4][4] = {};
  const int lr = tid >> 2;       // 0..63: tile row handled (and +64)
  const int lk = (tid & 3) * 8;  // k-offset 0,8,16,24

  for (int k0 = 0; k0 < K; k0 += TBK) {
#pragma unroll
    for (int h = 0; h < 2; h++) {
      int r = lr + h * 64;
      int grow = rowBase + r;
      uint4 va = make_uint4(0, 0, 0, 0);
      if (grow < M) va = *(const uint4*)(A + (size_t)grow * K + k0 + lk);
      *(uint4*)&As[r][lk] = va;
      int gcol = colBase + r;
      uint4 vb = make_uint4(0, 0, 0, 0);
      if (gcol < N) vb = *(const uint4*)(Bt + (size_t)gcol * K + k0 + lk);
      *(uint4*)&Bs[r][lk] = vb;
    }
    __syncthreads();
    bf16x8 af[4], bfr[4];
#pragma unroll
    for (int i = 0; i < 4; i++) {
      af[i]  = *(const bf16x8*)&As[wm * 64 + i * 16 + l16][quad * 8];
      bfr[i] = *(const bf16x8*)&Bs[wn * 64 + i * 16 + l16][quad * 8];
    }
#pragma unroll
    for (int i = 0; i < 4; i++)
#pragma unroll
      for (int j = 0; j < 4; j++)
        acc[i][j] = __builtin_amdgcn_mfma_f32_16x16x32_bf16(af[i], bfr[j], acc[i][j], 0, 0, 0);
    __syncthreads();
  }
#pragma unroll
  for (int i = 0; i < 4; i++) {
    int row0 = rowBase + wm * 64 + i * 16 + quad * 4;
#pragma unroll
    for (int j = 0; j < 4; j++) {
      int col = colBase + wn * 64 + j * 16 + l16;
      if (col >= N) continue;
      float bv = bias ? bias[col] : 0.f;
#pragma unroll
      for (int r = 0; r < 4; r++) {
        int row = row0 + r;
        if (row >= M) continue;
        float v = acc[i][j][r] + bv;
        if (OUT_BF16) ((ushort*)Cout)[(size_t)row * N + col] = f2bf(v);
        else          ((float*)Cout)[(size_t)row * N + col] = v;
      }
    }
  }
}

// ---------------- aggregation (gather), F=128 bf16 in ----------------
// out[n] = sum_e coef_e * h[src_e] + dinv[n]^2 * h[n] (+ bias)
// 1 wave per node, lane f handles features (2f, 2f+1) packed in one uint.
template <bool OUT_BF16>
__global__ __launch_bounds__(256) void agg_kernel(
    const ushort* __restrict__ hb, const int* __restrict__ rowptr,
    const int* __restrict__ srcs, const float* __restrict__ coefs,
    const float* __restrict__ dinv, const float* __restrict__ bias,
    void* __restrict__ out, int Nn) {
  const int wave = threadIdx.x >> 6;
  const int n = blockIdx.x * 4 + wave;
  if (n >= Nn) return;
  const int f = threadIdx.x & 63;
  const uint* h32 = (const uint*)hb;
  const float di = dinv[n];
  uint self = h32[(size_t)n * 64 + f];
  float a0 = bf2f((ushort)(self & 0xffffu)) * di * di;
  float a1 = bf2f((ushort)(self >> 16)) * di * di;
  if (bias) { a0 += bias[2 * f]; a1 += bias[2 * f + 1]; }
  int i = rowptr[n];
  const int e = rowptr[n + 1];
  for (; i + 3 < e; i += 4) {
    int s0 = srcs[i], s1 = srcs[i + 1], s2 = srcs[i + 2], s3 = srcs[i + 3];
    float c0 = coefs[i], c1 = coefs[i + 1], c2 = coefs[i + 2], c3 = coefs[i + 3];
    uint v0 = h32[(size_t)s0 * 64 + f];
    uint v1 = h32[(size_t)s1 * 64 + f];
    uint v2 = h32[(size_t)s2 * 64 + f];
    uint v3 = h32[(size_t)s3 * 64 + f];
    a0 += c0 * bf2f((ushort)(v0 & 0xffffu)) + c1 * bf2f((ushort)(v1 & 0xffffu)) +
          c2 * bf2f((ushort)(v2 & 0xffffu)) + c3 * bf2f((ushort)(v3 & 0xffffu));
    a1 += c0 * bf2f((ushort)(v0 >> 16)) + c1 * bf2f((ushort)(v1 >> 16)) +
          c2 * bf2f((ushort)(v2 >> 16)) + c3 * bf2f((ushort)(v3 >> 16));
  }
  for (; i < e; i++) {
    float c = coefs[i];
    uint v = h32[(size_t)srcs[i] * 64 + f];
    a0 += c * bf2f((ushort)(v & 0xffffu));
    a1 += c * bf2f((ushort)(v >> 16));
  }
  if (OUT_BF16) {
    uint o = (uint)f2bf(a0) | ((uint)f2bf(a1) << 16);
    ((uint*)out)[(size_t)n * 64 + f] = o;
  } else {
    ((float2*)out)[(size_t)n * 64 + f] = make_float2(a0, a1);
  }
}

// ---------------- LayerNorm + ELU ----------------
template <int F, bool IN_BF16>
__global__ __launch_bounds__(F) void ln_elu_kernel(const void* __restrict__ xin,
                                                   const float* __restrict__ g,
                                                   const float* __restrict__ be,
                                                   ushort* __restrict__ out) {
  constexpr int NW = (F + 63) / 64;
  __shared__ float sb[NW];
  const int row = blockIdx.x;
  const int f = threadIdx.x;
  float v;
  if (IN_BF16) v = bf2f(((const ushort*)xin)[(size_t)row * F + f]);
  else         v = ((const float*)xin)[(size_t)row * F + f];
  float s = v;
#pragma unroll
  for (int o = 32; o >= 1; o >>= 1) s += __shfl_xor(s, o);
  float mean;
  if constexpr (NW == 1) {
    mean = s * (1.0f / F);
  } else {
    if ((f & 63) == 0) sb[f >> 6] = s;
    __syncthreads();
    float t = 0.f;
#pragma unroll
    for (int w2 = 0; w2 < NW; w2++) t += sb[w2];
    mean = t * (1.0f / F);
    __syncthreads();
  }
  float d = v - mean;
  float q = d * d;
#pragma unroll
  for (int o = 32; o >= 1; o >>= 1) q += __shfl_xor(q, o);
  float var;
  if constexpr (NW == 1) {
    var = q * (1.0f / F);
  } else {
    if ((f & 63) == 0) sb[f >> 6] = q;
    __syncthreads();
    float t = 0.f;
#pragma unroll
    for (int w2 = 0; w2 < NW; w2++) t += sb[w2];
    var = t * (1.0f / F);
  }
  float y = d * rsqrtf(var + LN_EPS) * g[f] + be[f];
  out[(size_t)row * F + f] = f2bf((y > 0.f) ? y : expm1f(y));
}

// ---------------- host ----------------

extern "C" void kernel_launch(void* const* d_in, const int* in_sizes, int n_in,
                              void* d_out, int out_size, void* d_ws, size_t ws_size,
                              hipStream_t stream) {
  const float* x   = (const float*)d_in[0];
  const int*   ei  = (const int*)d_in[1];
  const float* W1  = (const float*)d_in[2];
  const float* b1  = (const float*)d_in[3];
  const float* g1  = (const float*)d_in[4];
  const float* be1 = (const float*)d_in[5];
  const float* W2  = (const float*)d_in[6];
  const float* b2  = (const float*)d_in[7];
  const float* g2  = (const float*)d_in[8];
  const float* be2 = (const float*)d_in[9];
  const float* W3  = (const float*)d_in[10];
  const float* b3  = (const float*)d_in[11];
  const float* g3  = (const float*)d_in[12];
  const float* be3 = (const float*)d_in[13];
  const float* Wl1 = (const float*)d_in[14];
  const float* bl1 = (const float*)d_in[15];
  const float* g4  = (const float*)d_in[16];
  const float* be4 = (const float*)d_in[17];
  const float* Wl2 = (const float*)d_in[18];
  const float* bl2 = (const float*)d_in[19];

  const int N = in_sizes[0] / 128;  // 50000
  const int E = in_sizes[1] / 2;    // 800000
  const int* esrc = ei;
  const int* edst = ei + E;

  // workspace layout (~84 MB)
  char* p = (char*)d_ws;
  float* F1 = (float*)p;              p += (size_t)N * 128 * 4;  // fp32 scratch [N][<=128]
  ushort* Pb = (ushort*)p;            p += (size_t)N * 256 * 2;  // bf16 act buf [N][<=256]
  ushort* Qb = (ushort*)p;            p += (size_t)N * 256 * 2;
  ushort* W1t = (ushort*)p;           p += 128 * 128 * 2;
  ushort* W2t = (ushort*)p;           p += 128 * 256 * 2;
  ushort* W3t = (ushort*)p;           p += 256 * 128 * 2;
  ushort* Wl1t = (ushort*)p;          p += 128 * 64 * 2;
  ushort* Wl2t = (ushort*)p;          p += 64 * 500 * 2;
  int*   srcs  = (int*)p;             p += (size_t)E * 4;
  float* coefs = (float*)p;           p += (size_t)E * 4;
  int*   deg   = (int*)p;             p += (size_t)N * 4;
  float* dinv  = (float*)p;           p += (size_t)N * 4;
  int*   rowptr= (int*)p;             p += (size_t)(N + 2) * 4;
  int*   fill  = (int*)p;             p += (size_t)N * 4;
  int*   bsums = (int*)p;             p += 256 * 4;
  ushort* xb = (ushort*)F1;  // overlay: xb dead before F1 first written

  const int nb = (N + 255) / 256;
  const int eb = (E + 255) / 256;

  // ---- CSR build ----
  zero2_kernel<<<nb, 256, 0, stream>>>(deg, fill, N);
  deg_kernel<<<eb, 256, 0, stream>>>(edst, deg, E);
  scan1_kernel<<<nb, 256, 0, stream>>>(deg, rowptr, bsums, dinv, N);
  scan2_kernel<<<1, 256, 0, stream>>>(bsums, nb);
  scan3_kernel<<<(N + 256) / 256, 256, 0, stream>>>(rowptr, bsums, N, E);
  fill_kernel<<<eb, 256, 0, stream>>>(esrc, edst, rowptr, fill, dinv, srcs, coefs, E);

  // ---- conversions ----
  f2bf_vec_kernel<<<(N * 128 / 4 + 255) / 256, 256, 0, stream>>>(x, xb, N * 128 / 4);
  WConvArgs wa;
  wa.w[0] = W1;  wa.wt[0] = W1t;  wa.K[0] = 128; wa.N[0] = 128;
  wa.w[1] = W2;  wa.wt[1] = W2t;  wa.K[1] = 128; wa.N[1] = 256;
  wa.w[2] = W3;  wa.wt[2] = W3t;  wa.K[2] = 256; wa.N[2] = 128;
  wa.w[3] = Wl1; wa.wt[3] = Wl1t; wa.K[3] = 128; wa.N[3] = 64;
  wa.w[4] = Wl2; wa.wt[4] = Wl2t; wa.K[4] = 64;  wa.N[4] = 500;
  wa.off[0] = 0;
  for (int m = 0; m < 5; m++) wa.off[m + 1] = wa.off[m] + wa.K[m] * wa.N[m];
  int wtotal = wa.off[5];
  wconv_kernel<<<(wtotal + 255) / 256, 256, 0, stream>>>(wa, wtotal);

  auto gemm_bf = [&](const ushort* A, const ushort* Bt, const float* bias, ushort* C,
                     int M, int Nn, int K) {
    dim3 grid((Nn + TBN - 1) / TBN, (M + TBM - 1) / TBM);
    mfma_gemm_kernel<true><<<grid, 256, 0, stream>>>(A, Bt, bias, C, M, Nn, K);
  };
  auto gemm_f32 = [&](const ushort* A, const ushort* Bt, const float* bias, float* C,
                      int M, int Nn, int K) {
    dim3 grid((Nn + TBN - 1) / TBN, (M + TBM - 1) / TBM);
    mfma_gemm_kernel<false><<<grid, 256, 0, stream>>>(A, Bt, bias, C, M, Nn, K);
  };
  const int ab = (N + 3) / 4;  // agg blocks (4 waves/block, 1 node/wave)

  // L1: h1 = elu(LN(Agg(x@W1) + b1))
  gemm_bf(xb, W1t, nullptr, Pb, N, 128, 128);                                   // Pb = x@W1 (bf16)
  agg_kernel<false><<<ab, 256, 0, stream>>>(Pb, rowptr, srcs, coefs, dinv, b1, F1, N);
  ln_elu_kernel<128, false><<<N, 128, 0, stream>>>(F1, g1, be1, Qb);            // Qb = h1

  // L2: h2 = elu(LN(Agg(h1)@W2 + b2))   (aggregate at F=128 before the 128->256 GEMM)
  agg_kernel<true><<<ab, 256, 0, stream>>>(Qb, rowptr, srcs, coefs, dinv, nullptr, Pb, N);
  gemm_bf(Pb, W2t, b2, Qb, N, 256, 128);                                        // Qb = g2 (bf16)
  ln_elu_kernel<256, true><<<N, 256, 0, stream>>>(Qb, g2, be2, Pb);             // Pb = h2

  // L3: h3 = elu(LN(Agg(h2@W3) + b3))   (GEMM 256->128 first, aggregate at F=128)
  gemm_bf(Pb, W3t, nullptr, Qb, N, 128, 256);                                   // Qb = h2@W3
  agg_kernel<false><<<ab, 256, 0, stream>>>(Qb, rowptr, srcs, coefs, dinv, b3, F1, N);
  ln_elu_kernel<128, false><<<N, 128, 0, stream>>>(F1, g3, be3, Pb);            // Pb = h3

  // L4: h4 = elu(LN(h3@Wl1 + bl1))
  gemm_f32(Pb, Wl1t, bl1, F1, N, 64, 128);                                      // F1 = g4 (fp32, fits)
  ln_elu_kernel<64, false><<<N, 64, 0, stream>>>(F1, g4, be4, Qb);              // Qb = h4

  // L5: out = h4@Wl2 + bl2
  gemm_f32(Qb, Wl2t, bl2, (float*)d_out, N, 500, 64);
}

// Round 3
// 529.726 us; speedup vs baseline: 1.3902x; 1.0861x over previous
//
#include <hip/hip_runtime.h>
#include <cstdint>

// ---------------------------------------------------------------------------
// GCNRecommender round 3:
//  - fill scatters only srcs (coef computed on-the-fly in agg from dinv table)
//  - fill cursor array pre-seeded with rowptr (atomicAdd gives absolute index)
//  - Agg + bias + LayerNorm + ELU fused for layers 1 and 3
//  - bf16 MFMA GEMMs (128x128 tile) unchanged from round 2
// ---------------------------------------------------------------------------

#define LN_EPS 1e-5f

typedef __attribute__((ext_vector_type(8))) short bf16x8;
typedef __attribute__((ext_vector_type(4))) float f32x4;

static __device__ __forceinline__ ushort f2bf(float f) {
  union { float f; uint u; } c; c.f = f;
  uint u = c.u;
  return (ushort)((u + 0x7fffu + ((u >> 16) & 1u)) >> 16);  // RNE
}
static __device__ __forceinline__ float bf2f(ushort h) {
  union { uint u; float f; } c; c.u = (uint)h << 16;
  return c.f;
}

// ---------------- CSR build ----------------

__global__ void zero1_kernel(int* __restrict__ a, int n) {
  int i = blockIdx.x * blockDim.x + threadIdx.x;
  if (i < n) a[i] = 0;
}

__global__ void deg_kernel(const int* __restrict__ dst, int* __restrict__ deg, int E) {
  int e = blockIdx.x * blockDim.x + threadIdx.x;
  if (e < E) atomicAdd(&deg[dst[e]], 1);
}

__global__ void scan1_kernel(const int* __restrict__ deg, int* __restrict__ excl,
                             int* __restrict__ bsums, float* __restrict__ dinv, int N) {
  __shared__ int s[256];
  int tid = threadIdx.x;
  int i = blockIdx.x * 256 + tid;
  int v = (i < N) ? deg[i] : 0;
  s[tid] = v;
  __syncthreads();
  for (int o = 1; o < 256; o <<= 1) {
    int t = (tid >= o) ? s[tid - o] : 0;
    __syncthreads();
    if (tid >= o) s[tid] += t;
    __syncthreads();
  }
  if (i < N) {
    excl[i] = s[tid] - v;
    dinv[i] = rsqrtf((float)v + 1.0f);  // +1 self-loop
  }
  if (tid == 255) bsums[blockIdx.x] = s[tid];
}

__global__ void scan2_kernel(int* __restrict__ bsums, int nb) {
  __shared__ int s[256];
  int tid = threadIdx.x;
  int v = (tid < nb) ? bsums[tid] : 0;
  s[tid] = v;
  __syncthreads();
  for (int o = 1; o < 256; o <<= 1) {
    int t = (tid >= o) ? s[tid - o] : 0;
    __syncthreads();
    if (tid >= o) s[tid] += t;
    __syncthreads();
  }
  if (tid < nb) bsums[tid] = s[tid] - v;
}

// finalize rowptr and seed the fill cursor with it
__global__ void scan3_kernel(int* __restrict__ rowptr, int* __restrict__ fill,
                             const int* __restrict__ bsums, int N, int Etotal) {
  int i = blockIdx.x * blockDim.x + threadIdx.x;
  if (i < N) {
    int v = rowptr[i] + bsums[i >> 8];
    rowptr[i] = v;
    fill[i] = v;
  } else if (i == N) {
    rowptr[N] = Etotal;
  }
}

__global__ void fill_kernel(const int* __restrict__ src, const int* __restrict__ dst,
                            int* __restrict__ fill, int* __restrict__ srcs, int E) {
  int e = blockIdx.x * blockDim.x + threadIdx.x;
  if (e >= E) return;
  int idx = atomicAdd(&fill[dst[e]], 1);
  srcs[idx] = src[e];
}

// ---------------- conversions ----------------

__global__ void f2bf_vec_kernel(const float* __restrict__ in, ushort* __restrict__ out, int n4) {
  int i = blockIdx.x * blockDim.x + threadIdx.x;
  if (i >= n4) return;
  float4 v = ((const float4*)in)[i];
  ushort4 o;
  o.x = f2bf(v.x); o.y = f2bf(v.y); o.z = f2bf(v.z); o.w = f2bf(v.w);
  ((ushort4*)out)[i] = o;
}

struct WConvArgs {
  const float* w[5];
  ushort* wt[5];
  int K[5], N[5];
  int off[6];
};

// W[K][N] fp32 -> Wt[N][K] bf16, all 5 weight matrices in one launch
__global__ void wconv_kernel(WConvArgs a, int total) {
  int i = blockIdx.x * blockDim.x + threadIdx.x;
  if (i >= total) return;
  int m = 0;
  while (i >= a.off[m + 1]) m++;
  int j = i - a.off[m];
  int k = j / a.N[m], n = j - k * a.N[m];
  a.wt[m][(size_t)n * a.K[m] + k] = f2bf(a.w[m][j]);
}

// ---------------- bf16 MFMA GEMM ----------------
// C[M][N] = A[M][K] @ Bt[N][K]^T (+ bias). K % 32 == 0.
#define TBM 128
#define TBN 128
#define TBK 32
#define LDK 40

template <bool OUT_BF16>
__global__ __launch_bounds__(256, 2) void mfma_gemm_kernel(
    const ushort* __restrict__ A, const ushort* __restrict__ Bt,
    const float* __restrict__ bias, void* __restrict__ Cout,
    int M, int N, int K) {
  __shared__ ushort As[TBM][LDK];
  __shared__ ushort Bs[TBN][LDK];
  const int tid = threadIdx.x;
  const int lane = tid & 63;
  const int w = tid >> 6;
  const int wm = w & 1, wn = w >> 1;
  const int quad = lane >> 4, l16 = lane & 15;
  const int rowBase = blockIdx.y * TBM;
  const int colBase = blockIdx.x * TBN;

  f32x4 acc[4][4] = {};
  const int lr = tid >> 2;
  const int lk = (tid & 3) * 8;

  for (int k0 = 0; k0 < K; k0 += TBK) {
#pragma unroll
    for (int h = 0; h < 2; h++) {
      int r = lr + h * 64;
      int grow = rowBase + r;
      uint4 va = make_uint4(0, 0, 0, 0);
      if (grow < M) va = *(const uint4*)(A + (size_t)grow * K + k0 + lk);
      *(uint4*)&As[r][lk] = va;
      int gcol = colBase + r;
      uint4 vb = make_uint4(0, 0, 0, 0);
      if (gcol < N) vb = *(const uint4*)(Bt + (size_t)gcol * K + k0 + lk);
      *(uint4*)&Bs[r][lk] = vb;
    }
    __syncthreads();
    bf16x8 af[4], bfr[4];
#pragma unroll
    for (int i = 0; i < 4; i++) {
      af[i]  = *(const bf16x8*)&As[wm * 64 + i * 16 + l16][quad * 8];
      bfr[i] = *(const bf16x8*)&Bs[wn * 64 + i * 16 + l16][quad * 8];
    }
#pragma unroll
    for (int i = 0; i < 4; i++)
#pragma unroll
      for (int j = 0; j < 4; j++)
        acc[i][j] = __builtin_amdgcn_mfma_f32_16x16x32_bf16(af[i], bfr[j], acc[i][j], 0, 0, 0);
    __syncthreads();
  }
#pragma unroll
  for (int i = 0; i < 4; i++) {
    int row0 = rowBase + wm * 64 + i * 16 + quad * 4;
#pragma unroll
    for (int j = 0; j < 4; j++) {
      int col = colBase + wn * 64 + j * 16 + l16;
      if (col >= N) continue;
      float bv = bias ? bias[col] : 0.f;
#pragma unroll
      for (int r = 0; r < 4; r++) {
        int row = row0 + r;
        if (row >= M) continue;
        float v = acc[i][j][r] + bv;
        if (OUT_BF16) ((ushort*)Cout)[(size_t)row * N + col] = f2bf(v);
        else          ((float*)Cout)[(size_t)row * N + col] = v;
      }
    }
  }
}

// ---------------- aggregation kernels, F=128 bf16 ----------------
// Edge coef computed on the fly: c = dinv[src] * dinv[n].
// 1 wave per node, lane f handles features (2f, 2f+1) packed in one uint.

// Plain agg (no bias, no LN) -> bf16  [used before L2 GEMM]
__global__ __launch_bounds__(256) void agg_kernel(
    const ushort* __restrict__ hb, const int* __restrict__ rowptr,
    const int* __restrict__ srcs, const float* __restrict__ dinv,
    uint* __restrict__ out, int Nn) {
  const int wave = threadIdx.x >> 6;
  const int n = blockIdx.x * 4 + wave;
  if (n >= Nn) return;
  const int f = threadIdx.x & 63;
  const uint* h32 = (const uint*)hb;
  const float di = dinv[n];
  uint self = h32[(size_t)n * 64 + f];
  float a0 = bf2f((ushort)(self & 0xffffu)) * di * di;
  float a1 = bf2f((ushort)(self >> 16)) * di * di;
  int i = rowptr[n];
  const int e = rowptr[n + 1];
  for (; i + 3 < e; i += 4) {
    int s0 = srcs[i], s1 = srcs[i + 1], s2 = srcs[i + 2], s3 = srcs[i + 3];
    float c0 = dinv[s0] * di, c1 = dinv[s1] * di, c2 = dinv[s2] * di, c3 = dinv[s3] * di;
    uint v0 = h32[(size_t)s0 * 64 + f];
    uint v1 = h32[(size_t)s1 * 64 + f];
    uint v2 = h32[(size_t)s2 * 64 + f];
    uint v3 = h32[(size_t)s3 * 64 + f];
    a0 += c0 * bf2f((ushort)(v0 & 0xffffu)) + c1 * bf2f((ushort)(v1 & 0xffffu)) +
          c2 * bf2f((ushort)(v2 & 0xffffu)) + c3 * bf2f((ushort)(v3 & 0xffffu));
    a1 += c0 * bf2f((ushort)(v0 >> 16)) + c1 * bf2f((ushort)(v1 >> 16)) +
          c2 * bf2f((ushort)(v2 >> 16)) + c3 * bf2f((ushort)(v3 >> 16));
  }
  for (; i < e; i++) {
    int s = srcs[i];
    float c = dinv[s] * di;
    uint v = h32[(size_t)s * 64 + f];
    a0 += c * bf2f((ushort)(v & 0xffffu));
    a1 += c * bf2f((ushort)(v >> 16));
  }
  out[(size_t)n * 64 + f] = (uint)f2bf(a0) | ((uint)f2bf(a1) << 16);
}

// Fused agg + bias + LayerNorm + ELU -> bf16  [layers 1 and 3]
__global__ __launch_bounds__(256) void agg_ln_kernel(
    const ushort* __restrict__ hb, const int* __restrict__ rowptr,
    const int* __restrict__ srcs, const float* __restrict__ dinv,
    const float* __restrict__ bias, const float* __restrict__ g,
    const float* __restrict__ be, uint* __restrict__ out, int Nn) {
  const int wave = threadIdx.x >> 6;
  const int n = blockIdx.x * 4 + wave;
  if (n >= Nn) return;
  const int f = threadIdx.x & 63;
  const uint* h32 = (const uint*)hb;
  const float di = dinv[n];
  uint self = h32[(size_t)n * 64 + f];
  float2 bv = ((const float2*)bias)[f];
  float a0 = bf2f((ushort)(self & 0xffffu)) * di * di + bv.x;
  float a1 = bf2f((ushort)(self >> 16)) * di * di + bv.y;
  int i = rowptr[n];
  const int e = rowptr[n + 1];
  for (; i + 3 < e; i += 4) {
    int s0 = srcs[i], s1 = srcs[i + 1], s2 = srcs[i + 2], s3 = srcs[i + 3];
    float c0 = dinv[s0] * di, c1 = dinv[s1] * di, c2 = dinv[s2] * di, c3 = dinv[s3] * di;
    uint v0 = h32[(size_t)s0 * 64 + f];
    uint v1 = h32[(size_t)s1 * 64 + f];
    uint v2 = h32[(size_t)s2 * 64 + f];
    uint v3 = h32[(size_t)s3 * 64 + f];
    a0 += c0 * bf2f((ushort)(v0 & 0xffffu)) + c1 * bf2f((ushort)(v1 & 0xffffu)) +
          c2 * bf2f((ushort)(v2 & 0xffffu)) + c3 * bf2f((ushort)(v3 & 0xffffu));
    a1 += c0 * bf2f((ushort)(v0 >> 16)) + c1 * bf2f((ushort)(v1 >> 16)) +
          c2 * bf2f((ushort)(v2 >> 16)) + c3 * bf2f((ushort)(v3 >> 16));
  }
  for (; i < e; i++) {
    int s = srcs[i];
    float c = dinv[s] * di;
    uint v = h32[(size_t)s * 64 + f];
    a0 += c * bf2f((ushort)(v & 0xffffu));
    a1 += c * bf2f((ushort)(v >> 16));
  }
  // LayerNorm over 128 features (2 per lane, 64 lanes) + ELU
  float s = a0 + a1;
#pragma unroll
  for (int o = 32; o >= 1; o >>= 1) s += __shfl_xor(s, o);
  float mean = s * (1.0f / 128.0f);
  float d0 = a0 - mean, d1 = a1 - mean;
  float q = d0 * d0 + d1 * d1;
#pragma unroll
  for (int o = 32; o >= 1; o >>= 1) q += __shfl_xor(q, o);
  float rstd = rsqrtf(q * (1.0f / 128.0f) + LN_EPS);
  float2 gv = ((const float2*)g)[f];
  float2 bev = ((const float2*)be)[f];
  float y0 = d0 * rstd * gv.x + bev.x;
  float y1 = d1 * rstd * gv.y + bev.y;
  y0 = (y0 > 0.f) ? y0 : expm1f(y0);
  y1 = (y1 > 0.f) ? y1 : expm1f(y1);
  out[(size_t)n * 64 + f] = (uint)f2bf(y0) | ((uint)f2bf(y1) << 16);
}

// ---------------- LayerNorm + ELU (standalone, L2 and L4) ----------------
template <int F, bool IN_BF16>
__global__ __launch_bounds__(F) void ln_elu_kernel(const void* __restrict__ xin,
                                                   const float* __restrict__ g,
                                                   const float* __restrict__ be,
                                                   ushort* __restrict__ out) {
  constexpr int NW = (F + 63) / 64;
  __shared__ float sb[NW];
  const int row = blockIdx.x;
  const int f = threadIdx.x;
  float v;
  if (IN_BF16) v = bf2f(((const ushort*)xin)[(size_t)row * F + f]);
  else         v = ((const float*)xin)[(size_t)row * F + f];
  float s = v;
#pragma unroll
  for (int o = 32; o >= 1; o >>= 1) s += __shfl_xor(s, o);
  float mean;
  if constexpr (NW == 1) {
    mean = s * (1.0f / F);
  } else {
    if ((f & 63) == 0) sb[f >> 6] = s;
    __syncthreads();
    float t = 0.f;
#pragma unroll
    for (int w2 = 0; w2 < NW; w2++) t += sb[w2];
    mean = t * (1.0f / F);
    __syncthreads();
  }
  float d = v - mean;
  float q = d * d;
#pragma unroll
  for (int o = 32; o >= 1; o >>= 1) q += __shfl_xor(q, o);
  float var;
  if constexpr (NW == 1) {
    var = q * (1.0f / F);
  } else {
    if ((f & 63) == 0) sb[f >> 6] = q;
    __syncthreads();
    float t = 0.f;
#pragma unroll
    for (int w2 = 0; w2 < NW; w2++) t += sb[w2];
    var = t * (1.0f / F);
  }
  float y = d * rsqrtf(var + LN_EPS) * g[f] + be[f];
  out[(size_t)row * F + f] = f2bf((y > 0.f) ? y : expm1f(y));
}

// ---------------- host ----------------

extern "C" void kernel_launch(void* const* d_in, const int* in_sizes, int n_in,
                              void* d_out, int out_size, void* d_ws, size_t ws_size,
                              hipStream_t stream) {
  const float* x   = (const float*)d_in[0];
  const int*   ei  = (const int*)d_in[1];
  const float* W1  = (const float*)d_in[2];
  const float* b1  = (const float*)d_in[3];
  const float* g1  = (const float*)d_in[4];
  const float* be1 = (const float*)d_in[5];
  const float* W2  = (const float*)d_in[6];
  const float* b2  = (const float*)d_in[7];
  const float* g2  = (const float*)d_in[8];
  const float* be2 = (const float*)d_in[9];
  const float* W3  = (const float*)d_in[10];
  const float* b3  = (const float*)d_in[11];
  const float* g3  = (const float*)d_in[12];
  const float* be3 = (const float*)d_in[13];
  const float* Wl1 = (const float*)d_in[14];
  const float* bl1 = (const float*)d_in[15];
  const float* g4  = (const float*)d_in[16];
  const float* be4 = (const float*)d_in[17];
  const float* Wl2 = (const float*)d_in[18];
  const float* bl2 = (const float*)d_in[19];

  const int N = in_sizes[0] / 128;  // 50000
  const int E = in_sizes[1] / 2;    // 800000
  const int* esrc = ei;
  const int* edst = ei + E;

  // workspace layout
  char* p = (char*)d_ws;
  float* F1 = (float*)p;              p += (size_t)N * 128 * 4;  // fp32 scratch
  ushort* Pb = (ushort*)p;            p += (size_t)N * 256 * 2;  // bf16 act buf
  ushort* Qb = (ushort*)p;            p += (size_t)N * 256 * 2;
  ushort* W1t = (ushort*)p;           p += 128 * 128 * 2;
  ushort* W2t = (ushort*)p;           p += 128 * 256 * 2;
  ushort* W3t = (ushort*)p;           p += 256 * 128 * 2;
  ushort* Wl1t = (ushort*)p;          p += 128 * 64 * 2;
  ushort* Wl2t = (ushort*)p;          p += 64 * 500 * 2;
  int*   srcs  = (int*)p;             p += (size_t)E * 4;
  int*   deg   = (int*)p;             p += (size_t)N * 4;
  float* dinv  = (float*)p;           p += (size_t)N * 4;
  int*   rowptr= (int*)p;             p += (size_t)(N + 2) * 4;
  int*   fill  = (int*)p;             p += (size_t)N * 4;
  int*   bsums = (int*)p;             p += 256 * 4;
  ushort* xb = (ushort*)F1;  // overlay: xb dead before F1 first written

  const int nb = (N + 255) / 256;
  const int eb = (E + 255) / 256;

  // ---- CSR build ----
  zero1_kernel<<<nb, 256, 0, stream>>>(deg, N);
  deg_kernel<<<eb, 256, 0, stream>>>(edst, deg, E);
  scan1_kernel<<<nb, 256, 0, stream>>>(deg, rowptr, bsums, dinv, N);
  scan2_kernel<<<1, 256, 0, stream>>>(bsums, nb);
  scan3_kernel<<<(N + 256) / 256, 256, 0, stream>>>(rowptr, fill, bsums, N, E);
  fill_kernel<<<eb, 256, 0, stream>>>(esrc, edst, fill, srcs, E);

  // ---- conversions ----
  f2bf_vec_kernel<<<(N * 128 / 4 + 255) / 256, 256, 0, stream>>>(x, xb, N * 128 / 4);
  WConvArgs wa;
  wa.w[0] = W1;  wa.wt[0] = W1t;  wa.K[0] = 128; wa.N[0] = 128;
  wa.w[1] = W2;  wa.wt[1] = W2t;  wa.K[1] = 128; wa.N[1] = 256;
  wa.w[2] = W3;  wa.wt[2] = W3t;  wa.K[2] = 256; wa.N[2] = 128;
  wa.w[3] = Wl1; wa.wt[3] = Wl1t; wa.K[3] = 128; wa.N[3] = 64;
  wa.w[4] = Wl2; wa.wt[4] = Wl2t; wa.K[4] = 64;  wa.N[4] = 500;
  wa.off[0] = 0;
  for (int m = 0; m < 5; m++) wa.off[m + 1] = wa.off[m] + wa.K[m] * wa.N[m];
  int wtotal = wa.off[5];
  wconv_kernel<<<(wtotal + 255) / 256, 256, 0, stream>>>(wa, wtotal);

  auto gemm_bf = [&](const ushort* A, const ushort* Bt, const float* bias, ushort* C,
                     int M, int Nn, int K) {
    dim3 grid((Nn + TBN - 1) / TBN, (M + TBM - 1) / TBM);
    mfma_gemm_kernel<true><<<grid, 256, 0, stream>>>(A, Bt, bias, C, M, Nn, K);
  };
  auto gemm_f32 = [&](const ushort* A, const ushort* Bt, const float* bias, float* C,
                      int M, int Nn, int K) {
    dim3 grid((Nn + TBN - 1) / TBN, (M + TBM - 1) / TBM);
    mfma_gemm_kernel<false><<<grid, 256, 0, stream>>>(A, Bt, bias, C, M, Nn, K);
  };
  const int ab = (N + 3) / 4;

  // L1: h1 = elu(LN(Agg(x@W1) + b1))
  gemm_bf(xb, W1t, nullptr, Pb, N, 128, 128);
  agg_ln_kernel<<<ab, 256, 0, stream>>>(Pb, rowptr, srcs, dinv, b1, g1, be1, (uint*)Qb, N);

  // L2: h2 = elu(LN(Agg(h1)@W2 + b2))
  agg_kernel<<<ab, 256, 0, stream>>>(Qb, rowptr, srcs, dinv, (uint*)Pb, N);
  gemm_bf(Pb, W2t, b2, Qb, N, 256, 128);
  ln_elu_kernel<256, true><<<N, 256, 0, stream>>>(Qb, g2, be2, Pb);

  // L3: h3 = elu(LN(Agg(h2@W3) + b3))
  gemm_bf(Pb, W3t, nullptr, Qb, N, 128, 256);
  agg_ln_kernel<<<ab, 256, 0, stream>>>(Qb, rowptr, srcs, dinv, b3, g3, be3, (uint*)Pb, N);

  // L4: h4 = elu(LN(h3@Wl1 + bl1))
  gemm_f32(Pb, Wl1t, bl1, F1, N, 64, 128);
  ln_elu_kernel<64, false><<<N, 64, 0, stream>>>(F1, g4, be4, Qb);

  // L5: out = h4@Wl2 + bl2
  gemm_f32(Qb, Wl2t, bl2, (float*)d_out, N, 500, 64);
}